// Round 6
// baseline (40.964 us; speedup 1.0000x reference)
//
#include <hip/hip_runtime.h>

namespace {
constexpr int Bn = 4, Dn = 4, Hn = 768, Wn = 768;
constexpr int HWc = Hn * Wn;                       // 589824
constexpr size_t DHWc = (size_t)Dn * HWc;          // 2359296
constexpr float BONUS = 10.0f;
constexpr int HSTRIP = 4;
constexpr int NSTRIP = Hn / HSTRIP;                // 192
constexpr int NBLK = Bn * NSTRIP;                  // 768 (== 3 per CU, % 8 == 0)
}

// load one h-row (all 4 d-planes, 6-wide w window) into dst[d][c]
__device__ __forceinline__ void load_row(float (&dst)[4][6], const float* __restrict__ base,
                                         int row, int w0, int wl, int wr) {
#pragma unroll
    for (int dd = 0; dd < 4; ++dd) {
        const float* ph = base + (size_t)dd * HWc + (size_t)row * Wn;
        const float4 q = *reinterpret_cast<const float4*>(ph + w0);
        dst[dd][0] = ph[wl];
        dst[dd][1] = q.x;
        dst[dd][2] = q.y;
        dst[dd][3] = q.z;
        dst[dd][4] = q.w;
        dst[dd][5] = ph[wr];
    }
}

// trivial row (h == 0 or h == 767): strict NMS impossible -> coords=(d,w,h), y=x
__device__ __forceinline__ void row_trivial(const float (&vc)[4][6],
                                            float* __restrict__ cb, float* __restrict__ yb,
                                            int h, int w0) {
    const float4 cx = make_float4((float)w0, (float)(w0 + 1), (float)(w0 + 2), (float)(w0 + 3));
    const float4 cy = make_float4((float)h, (float)h, (float)h, (float)h);
#pragma unroll
    for (int d = 0; d < 4; ++d) {
        const size_t sp = (size_t)d * HWc + (size_t)h * Wn + (size_t)w0;
        *reinterpret_cast<float4*>(cb + sp)            = make_float4((float)d, (float)d, (float)d, (float)d);
        *reinterpret_cast<float4*>(cb + DHWc + sp)     = cx;
        *reinterpret_cast<float4*>(cb + 2 * DHWc + sp) = cy;
        *reinterpret_cast<float4*>(yb + sp)            = make_float4(vc[d][1], vc[d][2], vc[d][3], vc[d][4]);
    }
}

// full row: vm = row h-1, vc = row h, vp = row h+1 (bit-identical to round-5 body)
__device__ __forceinline__ void compute_row(const float (&vm)[4][6], const float (&vc)[4][6],
                                            const float (&vp)[4][6],
                                            float* __restrict__ cb, float* __restrict__ yb,
                                            int h, int w0) {
#pragma clang fp contract(off)
    const float4 cx = make_float4((float)w0, (float)(w0 + 1), (float)(w0 + 2), (float)(w0 + 3));
    const float4 cy = make_float4((float)h, (float)h, (float)h, (float)h);

    // d = 0 and d = 3: trivial (strict NMS impossible vs replicated self)
    {
        const size_t sp0 = (size_t)h * Wn + (size_t)w0;
        *reinterpret_cast<float4*>(cb + sp0)            = make_float4(0.f, 0.f, 0.f, 0.f);
        *reinterpret_cast<float4*>(cb + DHWc + sp0)     = cx;
        *reinterpret_cast<float4*>(cb + 2 * DHWc + sp0) = cy;
        *reinterpret_cast<float4*>(yb + sp0)            = make_float4(vc[0][1], vc[0][2], vc[0][3], vc[0][4]);
        const size_t sp3 = 3 * (size_t)HWc + sp0;
        *reinterpret_cast<float4*>(cb + sp3)            = make_float4(3.f, 3.f, 3.f, 3.f);
        *reinterpret_cast<float4*>(cb + DHWc + sp3)     = cx;
        *reinterpret_cast<float4*>(cb + 2 * DHWc + sp3) = cy;
        *reinterpret_cast<float4*>(yb + sp3)            = make_float4(vc[3][1], vc[3][2], vc[3][3], vc[3][4]);
    }

#pragma unroll
    for (int d = 1; d <= 2; ++d) {
        const int s0 = d - 1;
        const int s2 = d + 1;
        float colNC[6], cmax[6];
#pragma unroll
        for (int c = 0; c < 6; ++c) {
            float m = vm[s0][c];
            m = fmaxf(m, vc[s0][c]);
            m = fmaxf(m, vp[s0][c]);
            m = fmaxf(m, vm[d][c]);
            m = fmaxf(m, vp[d][c]);
            m = fmaxf(m, vm[s2][c]);
            m = fmaxf(m, vc[s2][c]);
            m = fmaxf(m, vp[s2][c]);
            colNC[c] = m;
            cmax[c] = fmaxf(m, vc[d][c]);
        }

        float outz[4], outx[4], outy[4], outv[4];
#pragma unroll
        for (int j = 0; j < 4; ++j) {
            const int cc = j + 1;
            const float xc = vc[d][cc];
            const float m = fmaxf(fmaxf(cmax[cc - 1], cmax[cc + 1]), fmaxf(colNC[cc], 0.0f));
            const bool nms = xc > m;

            const float gx  = 0.5f * (vc[d][cc + 1] - vc[d][cc - 1]);
            const float gy  = 0.5f * (vp[d][cc] - vm[d][cc]);
            const float gs  = 0.5f * (vc[s2][cc] - vc[s0][cc]);
            const float dxx = vc[d][cc + 1] - 2.0f * xc + vc[d][cc - 1];
            const float dyy = vp[d][cc] - 2.0f * xc + vm[d][cc];
            const float dss = vc[s2][cc] - 2.0f * xc + vc[s0][cc];
            const float dxy =  0.25f * (vp[d][cc + 1] - vp[d][cc - 1] - vm[d][cc + 1] + vm[d][cc - 1]);
            const float dys = -0.25f * (vp[s2][cc] - vm[s2][cc] - vp[s0][cc] + vm[s0][cc]);
            const float dxs = -0.25f * (vc[s2][cc + 1] - vc[s2][cc - 1] - vc[s0][cc + 1] + vc[s0][cc - 1]);

            const float cf00 = dyy * dss - dys * dys;
            const float cf01 = dxy * dss - dys * dxs;
            const float cf02 = dxy * dys - dyy * dxs;
            const float det  = dxx * cf00 - dxy * cf01 + dxs * cf02;
            const bool solved = fabsf(det) > 0.0f;
            const float sd = solved ? det : 1.0f;

            const float t0 = gy * dss - dys * gs;
            const float sx = (gx * cf00 - dxy * t0 + dxs * (gy * dys - dyy * gs)) / sd;
            const float sy = (dxx * t0 - gx * cf01 + dxs * (dxy * gs - gy * dxs)) / sd;
            const float ss = (dxx * (dyy * gs - gy * dys) - dxy * (dxy * gs - gy * dxs) + gx * cf02) / sd;

            const bool valid = nms && solved;
            float dxv = valid ? -sx : 0.0f;
            float dyv = valid ? -sy : 0.0f;
            float dsv = valid ? -ss : 0.0f;
            const float mx = fmaxf(fmaxf(fabsf(dxv), fabsf(dyv)), fabsf(dsv));
            if (mx > 0.7f) { dxv = 0.0f; dyv = 0.0f; dsv = 0.0f; }

            const float dy_ = 0.5f * (gx * dxv + gy * dyv + gs * dsv);
            float y = xc + dy_;
            if (valid) y += BONUS;

            outz[j] = (float)d + dsv;
            outx[j] = (float)(w0 + j) + dxv;
            outy[j] = (float)h + dyv;
            outv[j] = y;
        }

        const size_t sp = (size_t)d * HWc + (size_t)h * Wn + (size_t)w0;
        *reinterpret_cast<float4*>(cb + sp)            = make_float4(outz[0], outz[1], outz[2], outz[3]);
        *reinterpret_cast<float4*>(cb + DHWc + sp)     = make_float4(outx[0], outx[1], outx[2], outx[3]);
        *reinterpret_cast<float4*>(cb + 2 * DHWc + sp) = make_float4(outy[0], outy[1], outy[2], outy[3]);
        *reinterpret_cast<float4*>(yb + sp)            = make_float4(outv[0], outv[1], outv[2], outv[3]);
    }
}

// Each block owns HSTRIP consecutive h-rows: 4-slot register window slides in h,
// prefetching one new row per iteration -> steady loads||compute||stores cadence.
__global__ __launch_bounds__(192) void cqi3d(const float* __restrict__ x,
                                             float* __restrict__ coords,
                                             float* __restrict__ ymax) {
#pragma clang fp contract(off)
    int id = blockIdx.x;
    id = (id & 7) * (NBLK >> 3) + (id >> 3);   // XCD-contiguous swizzle (768 % 8 == 0)
    const int strip = id % NSTRIP;
    const int b = id / NSTRIP;
    const int h0 = strip * HSTRIP;
    const int t = threadIdx.x;
    const int w0 = t << 2;

    const float* base = x + (size_t)b * DHWc;
    float* cb = coords + (size_t)b * 3 * DHWc;
    float* yb = ymax + (size_t)b * DHWc;
    const int wl = (w0 == 0) ? 0 : w0 - 1;
    const int wr = (w0 + 4 < Wn) ? w0 + 4 : Wn - 1;

    if (strip == 0 || strip == NSTRIP - 1) {
        // boundary strips (16 blocks total): per-row independent with h-clamps
        for (int i = 0; i < HSTRIP; ++i) {
            const int hh = h0 + i;
            float vm[4][6], vc[4][6], vp[4][6];
            load_row(vc, base, hh, w0, wl, wr);
            if (hh == 0 || hh == Hn - 1) {
                row_trivial(vc, cb, yb, hh, w0);
                continue;
            }
            load_row(vm, base, hh - 1, w0, wl, wr);
            load_row(vp, base, hh + 1, w0, wl, wr);
            compute_row(vm, vc, vp, cb, yb, hh, w0);
        }
        return;
    }

    // interior strip: rows h0-1 .. h0+4 all exist, zero h-clamps
    float v[4][4][6];
    load_row(v[0], base, h0 - 1, w0, wl, wr);
    load_row(v[1], base, h0,     w0, wl, wr);
    load_row(v[2], base, h0 + 1, w0, wl, wr);
#pragma unroll
    for (int i = 0; i < HSTRIP; ++i) {
        const int hh = h0 + i;
        if (i < HSTRIP - 1)
            load_row(v[(i + 3) & 3], base, hh + 2, w0, wl, wr);   // prefetch next row
        compute_row(v[i & 3], v[(i + 1) & 3], v[(i + 2) & 3], cb, yb, hh, w0);
    }
}

extern "C" void kernel_launch(void* const* d_in, const int* in_sizes, int n_in,
                              void* d_out, int out_size, void* d_ws, size_t ws_size,
                              hipStream_t stream) {
    const float* x = (const float*)d_in[0];
    float* out = (float*)d_out;
    float* coords = out;                          // (B,1,3,D,H,W) flat
    float* ymaxp  = out + (size_t)Bn * 3 * DHWc;  // (B,1,D,H,W) flat
    cqi3d<<<dim3(NBLK), dim3(192, 1, 1), 0, stream>>>(x, coords, ymaxp);
}

// Round 8
// 36.941 us; speedup vs baseline: 1.1089x; 1.1089x over previous
//
#include <hip/hip_runtime.h>

namespace {
constexpr int Bn = 4, Dn = 4, Hn = 768, Wn = 768;
constexpr int HWc = Hn * Wn;                       // 589824
constexpr size_t DHWc = (size_t)Dn * HWc;          // 2359296
constexpr float BONUS = 10.0f;
}

typedef float floatx4 __attribute__((ext_vector_type(4)));

__device__ __forceinline__ void stnt(float* p, float a, float b, float c, float d) {
    floatx4 v = {a, b, c, d};
    __builtin_nontemporal_store(v, reinterpret_cast<floatx4*>(p));
}

// R5 structure (3072 blocks, one (b,h) row each, 4-wide w windows, d folded),
// plus: nontemporal output stores (write-only streams, don't thrash L2) and
// d-plane liveness reorder (plane 3 loaded after d=1 compute frees plane 0)
// to cut peak VGPR -> more resident waves -> more outstanding memory ops.
__global__ __launch_bounds__(192) void cqi3d(const float* __restrict__ x,
                                             float* __restrict__ coords,
                                             float* __restrict__ ymax) {
#pragma clang fp contract(off)
    int id = blockIdx.x;
    id = (id & 7) * ((Hn * Bn) >> 3) + (id >> 3);   // XCD-contiguous swizzle
    const int h = id % Hn;
    const int b = id / Hn;
    const int t = threadIdx.x;
    const int w0 = t << 2;

    const float* base = x + (size_t)b * DHWc;
    float* cb = coords + (size_t)b * 3 * DHWc;
    float* yb = ymax + (size_t)b * DHWc;

    const float fw0 = (float)w0, fw1 = (float)(w0 + 1), fw2 = (float)(w0 + 2), fw3 = (float)(w0 + 3);
    const float fh = (float)h;

    if (h == 0 || h == Hn - 1) {
        // boundary row: every voxel trivial; only center-row loads needed
#pragma unroll
        for (int d = 0; d < 4; ++d) {
            const size_t sp = (size_t)d * HWc + (size_t)h * Wn + (size_t)w0;
            const float4 q = *reinterpret_cast<const float4*>(base + sp);
            stnt(cb + sp,            (float)d, (float)d, (float)d, (float)d);
            stnt(cb + DHWc + sp,     fw0, fw1, fw2, fw3);
            stnt(cb + 2 * DHWc + sp, fh, fh, fh, fh);
            stnt(yb + sp,            q.x, q.y, q.z, q.w);
        }
        return;
    }

    const int wl = (w0 == 0) ? 0 : w0 - 1;
    const int wr = (w0 + 4 < Wn) ? w0 + 4 : Wn - 1;
    const int hz[3] = {h - 1, h, h + 1};

    // Window planes held separately so the compiler can free p0 before p3 loads.
    // p*[a][c]: a = h-axis, c: 0 = w0-1, 1..4 = w0..w0+3, 5 = w0+4
    float p0[3][6], p1[3][6], p2[3][6], p3[3][6];

#define LOAD_PLANE(P, DD)                                                        \
    {                                                                            \
        _Pragma("unroll")                                                        \
        for (int a = 0; a < 3; ++a) {                                            \
            const float* ph = base + (size_t)(DD) * HWc + (size_t)hz[a] * Wn;    \
            const float4 q = *reinterpret_cast<const float4*>(ph + w0);          \
            P[a][0] = ph[wl];                                                    \
            P[a][1] = q.x;  P[a][2] = q.y;  P[a][3] = q.z;  P[a][4] = q.w;       \
            P[a][5] = ph[wr];                                                    \
        }                                                                        \
    }

    LOAD_PLANE(p0, 0)
    LOAD_PLANE(p1, 1)
    LOAD_PLANE(p2, 2)

    // d=0 trivial outputs (center row of plane 0)
    {
        const size_t sp0 = (size_t)h * Wn + (size_t)w0;
        stnt(cb + sp0,            0.f, 0.f, 0.f, 0.f);
        stnt(cb + DHWc + sp0,     fw0, fw1, fw2, fw3);
        stnt(cb + 2 * DHWc + sp0, fh, fh, fh, fh);
        stnt(yb + sp0,            p0[1][1], p0[1][2], p0[1][3], p0[1][4]);
    }

    // identical arithmetic to round 5 for the solve (bit-exact requirement)
#define COMPUTE_D(PL, PC, PR, DVAL)                                                              \
    {                                                                                            \
        float colNC[6], cmax[6];                                                                 \
        _Pragma("unroll")                                                                        \
        for (int c = 0; c < 6; ++c) {                                                            \
            float m = PL[0][c];                                                                  \
            m = fmaxf(m, PL[1][c]);                                                              \
            m = fmaxf(m, PL[2][c]);                                                              \
            m = fmaxf(m, PC[0][c]);                                                              \
            m = fmaxf(m, PC[2][c]);                                                              \
            m = fmaxf(m, PR[0][c]);                                                              \
            m = fmaxf(m, PR[1][c]);                                                              \
            m = fmaxf(m, PR[2][c]);                                                              \
            colNC[c] = m;                                                                        \
            cmax[c] = fmaxf(m, PC[1][c]);                                                        \
        }                                                                                        \
        float outz[4], outx[4], outy[4], outv[4];                                                \
        _Pragma("unroll")                                                                        \
        for (int j = 0; j < 4; ++j) {                                                            \
            const int cc = j + 1;                                                                \
            const float xc = PC[1][cc];                                                          \
            const float m = fmaxf(fmaxf(cmax[cc - 1], cmax[cc + 1]), fmaxf(colNC[cc], 0.0f));    \
            const bool nms = xc > m;                                                             \
            const float gx  = 0.5f * (PC[1][cc + 1] - PC[1][cc - 1]);                            \
            const float gy  = 0.5f * (PC[2][cc] - PC[0][cc]);                                    \
            const float gs  = 0.5f * (PR[1][cc] - PL[1][cc]);                                    \
            const float dxx = PC[1][cc + 1] - 2.0f * xc + PC[1][cc - 1];                         \
            const float dyy = PC[2][cc] - 2.0f * xc + PC[0][cc];                                 \
            const float dss = PR[1][cc] - 2.0f * xc + PL[1][cc];                                 \
            const float dxy =  0.25f * (PC[2][cc + 1] - PC[2][cc - 1] - PC[0][cc + 1] + PC[0][cc - 1]); \
            const float dys = -0.25f * (PR[2][cc] - PL[2][cc] - PR[0][cc] + PL[0][cc]);          \
            const float dxs = -0.25f * (PR[1][cc + 1] - PR[1][cc - 1] - PL[1][cc + 1] + PL[1][cc - 1]); \
            const float cf00 = dyy * dss - dys * dys;                                            \
            const float cf01 = dxy * dss - dys * dxs;                                            \
            const float cf02 = dxy * dys - dyy * dxs;                                            \
            const float det  = dxx * cf00 - dxy * cf01 + dxs * cf02;                             \
            const bool solved = fabsf(det) > 0.0f;                                               \
            const float sd = solved ? det : 1.0f;                                                \
            const float t0 = gy * dss - dys * gs;                                                \
            const float sx = (gx * cf00 - dxy * t0 + dxs * (gy * dys - dyy * gs)) / sd;          \
            const float sy = (dxx * t0 - gx * cf01 + dxs * (dxy * gs - gy * dxs)) / sd;          \
            const float ss = (dxx * (dyy * gs - gy * dys) - dxy * (dxy * gs - gy * dxs) + gx * cf02) / sd; \
            const bool valid = nms && solved;                                                    \
            float dxv = valid ? -sx : 0.0f;                                                      \
            float dyv = valid ? -sy : 0.0f;                                                      \
            float dsv = valid ? -ss : 0.0f;                                                      \
            const float mx = fmaxf(fmaxf(fabsf(dxv), fabsf(dyv)), fabsf(dsv));                   \
            if (mx > 0.7f) { dxv = 0.0f; dyv = 0.0f; dsv = 0.0f; }                               \
            const float dy_ = 0.5f * (gx * dxv + gy * dyv + gs * dsv);                           \
            float y = xc + dy_;                                                                  \
            if (valid) y += BONUS;                                                               \
            outz[j] = (float)(DVAL) + dsv;                                                       \
            outx[j] = (float)(w0 + j) + dxv;                                                     \
            outy[j] = fh + dyv;                                                                  \
            outv[j] = y;                                                                         \
        }                                                                                        \
        const size_t sp = (size_t)(DVAL) * HWc + (size_t)h * Wn + (size_t)w0;                    \
        stnt(cb + sp,            outz[0], outz[1], outz[2], outz[3]);                            \
        stnt(cb + DHWc + sp,     outx[0], outx[1], outx[2], outx[3]);                            \
        stnt(cb + 2 * DHWc + sp, outy[0], outy[1], outy[2], outy[3]);                            \
        stnt(yb + sp,            outv[0], outv[1], outv[2], outv[3]);                            \
    }

    // d = 1 uses planes 0,1,2; after this, plane 0 is dead
    COMPUTE_D(p0, p1, p2, 1)

    // now load plane 3 (reuses plane 0's registers) and finish d=2 + d=3 trivial
    LOAD_PLANE(p3, 3)

    {
        const size_t sp3 = 3 * (size_t)HWc + (size_t)h * Wn + (size_t)w0;
        stnt(cb + sp3,            3.f, 3.f, 3.f, 3.f);
        stnt(cb + DHWc + sp3,     fw0, fw1, fw2, fw3);
        stnt(cb + 2 * DHWc + sp3, fh, fh, fh, fh);
        stnt(yb + sp3,            p3[1][1], p3[1][2], p3[1][3], p3[1][4]);
    }

    COMPUTE_D(p1, p2, p3, 2)

#undef LOAD_PLANE
#undef COMPUTE_D
}

extern "C" void kernel_launch(void* const* d_in, const int* in_sizes, int n_in,
                              void* d_out, int out_size, void* d_ws, size_t ws_size,
                              hipStream_t stream) {
    const float* x = (const float*)d_in[0];
    float* out = (float*)d_out;
    float* coords = out;                          // (B,1,3,D,H,W) flat
    float* ymaxp  = out + (size_t)Bn * 3 * DHWc;  // (B,1,D,H,W) flat
    cqi3d<<<dim3(Hn * Bn), dim3(192, 1, 1), 0, stream>>>(x, coords, ymaxp);
}